// Round 6
// baseline (552.351 us; speedup 1.0000x reference)
//
#include <hip/hip_runtime.h>
#include <cstddef>

#define GG 2048
#define PP 18
#define NNODE (GG*PP)      // 36864
#define EPG 306            // directed edges per graph (17*18)
#define F1 128             // H1*C1
#define F2 256             // H2*C2
#define XP1 132            // padded xl/xr row stride (f32), gat1
#define XP2 260            // padded xl/xr row stride (f32), gat2
#define INF 6

typedef unsigned short u16;
typedef __attribute__((ext_vector_type(8))) short short8;   // 8 bf16
typedef __attribute__((ext_vector_type(4))) float f32x4;

__device__ __forceinline__ float lrelu(float v) { return v > 0.f ? v : 0.01f * v; }

__device__ __forceinline__ u16 f2b(float x) {            // fp32 -> bf16 RNE
    union { float f; unsigned u; } c; c.f = x;
    unsigned r = c.u + 0x7FFF + ((c.u >> 16) & 1);
    return (u16)(r >> 16);
}
__device__ __forceinline__ float b2f(u16 v) {
    union { unsigned u; float f; } c; c.u = ((unsigned)v) << 16;
    return c.f;
}

// ================= layer 1: GATv2 (6 -> 4x32) + BN1 stats, one block/graph =================
__global__ __launch_bounds__(256) void gat1_kernel(
    const float* __restrict__ x, const float* __restrict__ eattr,
    const float* __restrict__ W1l, const float* __restrict__ b1l,
    const float* __restrict__ W1r, const float* __restrict__ b1r,
    const float* __restrict__ We1, const float* __restrict__ att1,
    const float* __restrict__ bias1, float* __restrict__ h1,
    float* __restrict__ sum1, float* __restrict__ ss1)
{
    __shared__ float xs[PP*INF];
    __shared__ float wl[INF*F1], wr[INF*F1];
    __shared__ float bl[F1], br[F1], we[F1], att[F1];
    __shared__ float ea[PP*PP];            // ea[s*18+d]
    __shared__ float xl[PP*XP1], xr[PP*XP1];
    __shared__ float alpha[PP*PP*4];       // [d*72 + s*4 + h]
    const int g = blockIdx.x, tid = threadIdx.x;

    if (tid < PP*INF) xs[tid] = x[g*PP*INF + tid];
    for (int i = tid; i < INF*F1; i += 256) { wl[i] = W1l[i]; wr[i] = W1r[i]; }
    if (tid < F1) { bl[tid]=b1l[tid]; br[tid]=b1r[tid]; we[tid]=We1[tid]; att[tid]=att1[tid]; }
    for (int t = tid; t < EPG; t += 256) {
        int s = t/17, pos = t%17;
        int d = pos + (pos >= s);
        ea[s*PP + d] = eattr[g*EPG + t];
    }
    __syncthreads();
    if (tid < PP) {   // self-loop attr = mean of incoming
        float sum = 0.f;
        for (int s = 0; s < PP; ++s) if (s != tid) sum += ea[s*PP + tid];
        ea[tid*PP + tid] = sum * (1.f/17.f);
    }
    __syncthreads();
    // projections (write into padded rows)
    for (int o = tid; o < PP*F1; o += 256) {
        int n = o >> 7, j = o & (F1-1);
        float al = bl[j], ar = br[j];
        #pragma unroll
        for (int k = 0; k < INF; ++k) {
            float xv = xs[n*INF + k];
            al = fmaf(xv, wl[k*F1 + j], al);
            ar = fmaf(xv, wr[k*F1 + j], ar);
        }
        xl[n*XP1 + j] = al; xr[n*XP1 + j] = ar;
    }
    __syncthreads();
    // alpha: thread <-> one (d,s,h) entry; quad-rotated b128 reads (no cross-lane ops)
    for (int t = tid; t < PP*PP*4; t += 256) {
        int h = t & 3, s = (t >> 2) % PP, d = t / (PP*4);
        float eav = ea[s*PP + d];
        int ja = h << 5;                   // h*32
        float acc = 0.f;
        #pragma unroll
        for (int cc = 0; cc < 8; ++cc) {
            int cq = ((cc + t) & 7) << 2;  // rotate quads over banks
            float4 xl4 = *(const float4*)&xl[s*XP1 + ja + cq];
            float4 xr4 = *(const float4*)&xr[d*XP1 + ja + cq];
            float4 we4 = *(const float4*)&we[ja + cq];
            float4 at4 = *(const float4*)&att[ja + cq];
            float p0 = lrelu(fmaf(eav, we4.x, xl4.x + xr4.x)) * at4.x;
            float p1 = lrelu(fmaf(eav, we4.y, xl4.y + xr4.y)) * at4.y;
            float p2 = lrelu(fmaf(eav, we4.z, xl4.z + xr4.z)) * at4.z;
            float p3 = lrelu(fmaf(eav, we4.w, xl4.w + xr4.w)) * at4.w;
            acc += (p0 + p1) + (p2 + p3);
        }
        alpha[t] = acc;
    }
    __syncthreads();
    if (tid < PP*4) {                      // softmax over s per (d,h)
        int d = tid >> 2, h = tid & 3;
        int base = d*(PP*4) + h;
        float m = -1e30f;
        for (int s = 0; s < PP; ++s) m = fmaxf(m, alpha[base + s*4]);
        float sum = 0.f;
        for (int s = 0; s < PP; ++s) sum += __expf(alpha[base + s*4] - m);
        float inv = 1.f/(sum + 1e-16f);
        for (int s = 0; s < PP; ++s)
            alpha[base + s*4] = __expf(alpha[base + s*4] - m) * inv;
    }
    __syncthreads();
    // PV: lane owns fixed column-quad jq = tid&31 (c0=4jq); contiguous b128 xl reads
    float4 s_loc = {0,0,0,0}, q_loc = {0,0,0,0};
    {
        const int jq = tid & 31, h = jq >> 3, c0 = jq << 2;
        const float4 b4 = *(const float4*)&bias1[c0];
        for (int slot = tid; slot < PP*32; slot += 256) {
            int d = slot >> 5;
            float4 acc = b4;
            for (int s = 0; s < PP; ++s) {
                float av = alpha[d*(PP*4) + s*4 + h];
                float4 x4 = *(const float4*)&xl[s*XP1 + c0];
                acc.x = fmaf(av, x4.x, acc.x); acc.y = fmaf(av, x4.y, acc.y);
                acc.z = fmaf(av, x4.z, acc.z); acc.w = fmaf(av, x4.w, acc.w);
            }
            *(float4*)&h1[(size_t)g*(PP*F1) + d*F1 + c0] = acc;
            s_loc.x += acc.x; s_loc.y += acc.y; s_loc.z += acc.z; s_loc.w += acc.w;
            q_loc.x = fmaf(acc.x, acc.x, q_loc.x); q_loc.y = fmaf(acc.y, acc.y, q_loc.y);
            q_loc.z = fmaf(acc.z, acc.z, q_loc.z); q_loc.w = fmaf(acc.w, acc.w, q_loc.w);
        }
    }
    __syncthreads();                       // xl/alpha reads done; reuse xl/xr as stage
    *(float4*)&xl[tid*4] = s_loc;
    *(float4*)&xr[tid*4] = q_loc;
    __syncthreads();
    if (tid < 32) {                        // lane owns columns 4*tid..4*tid+3
        float4 S = {0,0,0,0}, Q = {0,0,0,0};
        #pragma unroll
        for (int m = 0; m < 8; ++m) {
            float4 a = *(const float4*)&xl[(tid + 32*m)*4];
            float4 b = *(const float4*)&xr[(tid + 32*m)*4];
            S.x+=a.x; S.y+=a.y; S.z+=a.z; S.w+=a.w;
            Q.x+=b.x; Q.y+=b.y; Q.z+=b.z; Q.w+=b.w;
        }
        atomicAdd(&sum1[4*tid+0], S.x); atomicAdd(&sum1[4*tid+1], S.y);
        atomicAdd(&sum1[4*tid+2], S.z); atomicAdd(&sum1[4*tid+3], S.w);
        atomicAdd(&ss1[4*tid+0], Q.x);  atomicAdd(&ss1[4*tid+1], Q.y);
        atomicAdd(&ss1[4*tid+2], Q.z);  atomicAdd(&ss1[4*tid+3], Q.w);
    }
}

// ================= BN finalize =================
__global__ void bnfin(const float* __restrict__ sum, const float* __restrict__ ss,
                      const float* __restrict__ gamma, const float* __restrict__ beta,
                      float* __restrict__ sc, float* __restrict__ sh, int C, float invN)
{
    int c = threadIdx.x + blockIdx.x*blockDim.x;
    if (c < C) {
        float mu = sum[c]*invN;
        float var = ss[c]*invN - mu*mu;
        float s = gamma[c]*rsqrtf(var + 1e-5f);
        sc[c] = s;
        sh[c] = beta[c] - mu*s;
    }
}

// ================= prep: W2 -> bf16 transposed, bias concat, zero stats =================
__global__ void prep_w(const float* __restrict__ W2l, const float* __restrict__ W2r,
                       const float* __restrict__ b2l, const float* __restrict__ b2r,
                       u16* __restrict__ wbt, float* __restrict__ biascat,
                       float* __restrict__ st)
{
    int t = blockIdx.x*blockDim.x + threadIdx.x;
    if (t < 1536) st[t] = 0.f;
    if (t < 512*128) {
        int c = t >> 7, k = t & 127;
        float v = (c < 256) ? W2l[k*256 + c] : W2r[k*256 + (c-256)];
        wbt[t] = f2b(v);           // wbt[c][k]
    } else if (t < 512*128 + 512) {
        int c = t - 512*128;
        biascat[c] = (c < 256) ? b2l[c] : b2r[c-256];
    }
}

// ================= layer-2 projection GEMM (bn1+lrelu fused into A-stage) =================
__global__ __launch_bounds__(256) void gemm2_kernel(
    const float* __restrict__ h1, const float* __restrict__ sc1, const float* __restrict__ sh1,
    const u16* __restrict__ wbt, const float* __restrict__ biascat, u16* __restrict__ xlr)
{
    __shared__ u16 As[64*128];
    __shared__ u16 Bs[64*128];
    __shared__ float scs[F1], shs[F1];
    const int b = blockIdx.x;
    const int bm = b >> 3, bn = b & 7;
    const int r0 = bm*64, c0 = bn*64;
    const int tid = threadIdx.x;

    if (tid < F1) { scs[tid] = sc1[tid]; shs[tid] = sh1[tid]; }
    __syncthreads();
    for (int i = tid*8; i < 64*128; i += 256*8) {
        int r = i >> 7, c = i & 127;
        float4 v0 = *(const float4*)&h1[(size_t)(r0+r)*128 + c];
        float4 v1 = *(const float4*)&h1[(size_t)(r0+r)*128 + c + 4];
        short8 a;
        a[0] = (short)f2b(lrelu(fmaf(scs[c+0], v0.x, shs[c+0])));
        a[1] = (short)f2b(lrelu(fmaf(scs[c+1], v0.y, shs[c+1])));
        a[2] = (short)f2b(lrelu(fmaf(scs[c+2], v0.z, shs[c+2])));
        a[3] = (short)f2b(lrelu(fmaf(scs[c+3], v0.w, shs[c+3])));
        a[4] = (short)f2b(lrelu(fmaf(scs[c+4], v1.x, shs[c+4])));
        a[5] = (short)f2b(lrelu(fmaf(scs[c+5], v1.y, shs[c+5])));
        a[6] = (short)f2b(lrelu(fmaf(scs[c+6], v1.z, shs[c+6])));
        a[7] = (short)f2b(lrelu(fmaf(scs[c+7], v1.w, shs[c+7])));
        int idx = i ^ ((r & 7) << 3);
        *reinterpret_cast<short8*>(&As[idx]) = a;
        *reinterpret_cast<short8*>(&Bs[idx]) =
            *reinterpret_cast<const short8*>(&wbt[(size_t)(c0+r)*128 + c]);
    }
    __syncthreads();

    const int w = tid >> 6, l = tid & 63;
    const int lr = l & 15, lk = (l >> 4) * 8;
    const int ar = w*16 + lr;
    f32x4 acc[4] = {f32x4{0,0,0,0}, f32x4{0,0,0,0}, f32x4{0,0,0,0}, f32x4{0,0,0,0}};

    #pragma unroll
    for (int kk = 0; kk < 4; ++kk) {
        int k0 = kk*32 + lk;
        short8 a = *reinterpret_cast<const short8*>(&As[(ar*128 + k0) ^ ((ar & 7) << 3)]);
        #pragma unroll
        for (int n = 0; n < 4; ++n) {
            int br = n*16 + lr;
            short8 bf = *reinterpret_cast<const short8*>(&Bs[(br*128 + k0) ^ ((br & 7) << 3)]);
            acc[n] = __builtin_amdgcn_mfma_f32_16x16x32_bf16(a, bf, acc[n], 0, 0, 0);
        }
    }
    const int rbase = r0 + w*16 + (l >> 4)*4;
    #pragma unroll
    for (int n = 0; n < 4; ++n) {
        int C = c0 + n*16 + lr;
        float bv = biascat[C];
        #pragma unroll
        for (int j = 0; j < 4; ++j) {
            xlr[(size_t)(rbase + j)*512 + C] = f2b(acc[n][j] + bv);
        }
    }
}

// ================= layer 2 attention + BN2 stats, one block/graph =================
__global__ __launch_bounds__(256) void gat2_attn(
    const u16* __restrict__ xlr, const float* __restrict__ eattr,
    const float* __restrict__ We2, const float* __restrict__ att2,
    const float* __restrict__ bias2, float* __restrict__ h2,
    float* __restrict__ sum2, float* __restrict__ ss2)
{
    __shared__ float xl[PP*XP2], xr[PP*XP2];
    __shared__ float ea[PP*PP];
    __shared__ float alpha[PP*PP*4];       // [d*72 + s*4 + h]
    __shared__ float we[F2], att[F2];
    const int g = blockIdx.x, tid = threadIdx.x;

    if (tid < F2) { we[tid] = We2[tid]; att[tid] = att2[tid]; }
    for (int i4 = tid; i4 < PP*128; i4 += 256) {     // 18*512 elems in quads
        int n = i4 >> 7, j = (i4 & 127) * 4;
        ushort4 v = *reinterpret_cast<const ushort4*>(&xlr[(size_t)(g*PP + n)*512 + j]);
        float4 f = make_float4(b2f(v.x), b2f(v.y), b2f(v.z), b2f(v.w));
        if (j < 256) *(float4*)&xl[n*XP2 + j] = f;
        else         *(float4*)&xr[n*XP2 + j - 256] = f;
    }
    for (int t = tid; t < EPG; t += 256) {
        int s = t/17, pos = t%17;
        int d = pos + (pos >= s);
        ea[s*PP + d] = eattr[g*EPG + t];
    }
    __syncthreads();
    if (tid < PP) {
        float sum = 0.f;
        for (int s = 0; s < PP; ++s) if (s != tid) sum += ea[s*PP + tid];
        ea[tid*PP + tid] = sum * (1.f/17.f);
    }
    __syncthreads();
    // alpha: thread <-> one (d,s,h) entry; quad-rotated b128 reads
    for (int t = tid; t < PP*PP*4; t += 256) {
        int h = t & 3, s = (t >> 2) % PP, d = t / (PP*4);
        float eav = ea[s*PP + d];
        int ja = h << 6;                   // h*64
        float acc = 0.f;
        #pragma unroll
        for (int cc = 0; cc < 16; ++cc) {
            int cq = ((cc + t) & 15) << 2;
            float4 xl4 = *(const float4*)&xl[s*XP2 + ja + cq];
            float4 xr4 = *(const float4*)&xr[d*XP2 + ja + cq];
            float4 we4 = *(const float4*)&we[ja + cq];
            float4 at4 = *(const float4*)&att[ja + cq];
            float p0 = lrelu(fmaf(eav, we4.x, xl4.x + xr4.x)) * at4.x;
            float p1 = lrelu(fmaf(eav, we4.y, xl4.y + xr4.y)) * at4.y;
            float p2 = lrelu(fmaf(eav, we4.z, xl4.z + xr4.z)) * at4.z;
            float p3 = lrelu(fmaf(eav, we4.w, xl4.w + xr4.w)) * at4.w;
            acc += (p0 + p1) + (p2 + p3);
        }
        alpha[t] = acc;
    }
    __syncthreads();
    if (tid < PP*4) {
        int d = tid >> 2, h = tid & 3;
        int base = d*(PP*4) + h;
        float m = -1e30f;
        for (int s = 0; s < PP; ++s) m = fmaxf(m, alpha[base + s*4]);
        float sum = 0.f;
        for (int s = 0; s < PP; ++s) sum += __expf(alpha[base + s*4] - m);
        float inv = 1.f/(sum + 1e-16f);
        for (int s = 0; s < PP; ++s)
            alpha[base + s*4] = __expf(alpha[base + s*4] - m) * inv;
    }
    __syncthreads();
    // PV: lane owns fixed column-quad jq = tid&63 (c0=4jq)
    float4 s_loc = {0,0,0,0}, q_loc = {0,0,0,0};
    {
        const int jq = tid & 63, h = jq >> 4, c0 = jq << 2;
        const float4 b4 = *(const float4*)&bias2[c0];
        for (int slot = tid; slot < PP*64; slot += 256) {
            int d = slot >> 6;
            float4 acc = b4;
            for (int s = 0; s < PP; ++s) {
                float av = alpha[d*(PP*4) + s*4 + h];
                float4 x4 = *(const float4*)&xl[s*XP2 + c0];
                acc.x = fmaf(av, x4.x, acc.x); acc.y = fmaf(av, x4.y, acc.y);
                acc.z = fmaf(av, x4.z, acc.z); acc.w = fmaf(av, x4.w, acc.w);
            }
            *(float4*)&h2[(size_t)g*(PP*F2) + d*F2 + c0] = acc;
            s_loc.x += acc.x; s_loc.y += acc.y; s_loc.z += acc.z; s_loc.w += acc.w;
            q_loc.x = fmaf(acc.x, acc.x, q_loc.x); q_loc.y = fmaf(acc.y, acc.y, q_loc.y);
            q_loc.z = fmaf(acc.z, acc.z, q_loc.z); q_loc.w = fmaf(acc.w, acc.w, q_loc.w);
        }
    }
    __syncthreads();                       // reuse xl/xr as stage
    *(float4*)&xl[tid*4] = s_loc;
    *(float4*)&xr[tid*4] = q_loc;
    __syncthreads();
    if (tid < 64) {                        // lane owns columns 4*tid..4*tid+3
        float4 S = {0,0,0,0}, Q = {0,0,0,0};
        #pragma unroll
        for (int m = 0; m < 4; ++m) {
            float4 a = *(const float4*)&xl[(tid + 64*m)*4];
            float4 b = *(const float4*)&xr[(tid + 64*m)*4];
            S.x+=a.x; S.y+=a.y; S.z+=a.z; S.w+=a.w;
            Q.x+=b.x; Q.y+=b.y; Q.z+=b.z; Q.w+=b.w;
        }
        atomicAdd(&sum2[4*tid+0], S.x); atomicAdd(&sum2[4*tid+1], S.y);
        atomicAdd(&sum2[4*tid+2], S.z); atomicAdd(&sum2[4*tid+3], S.w);
        atomicAdd(&ss2[4*tid+0], Q.x);  atomicAdd(&ss2[4*tid+1], Q.y);
        atomicAdd(&ss2[4*tid+2], Q.z);  atomicAdd(&ss2[4*tid+3], Q.w);
    }
}

// ================= BN2+lrelu + mean-pool + MLP head, 8 graphs/block =================
__global__ __launch_bounds__(256) void mlp_kernel(
    const float* __restrict__ h2, const float* __restrict__ sc2, const float* __restrict__ sh2,
    const float* __restrict__ Wfc1, const float* __restrict__ bfc1,
    const float* __restrict__ Wfc2, const float* __restrict__ bfc2,
    const float* __restrict__ Wfc3, const float* __restrict__ bfc3,
    float* __restrict__ out)
{
    __shared__ float pooled[8][F2];
    __shared__ float y1[8][512];
    __shared__ float y2[8][128];
    const int g0 = blockIdx.x * 8, tid = threadIdx.x;
    const float scv = sc2[tid], shv = sh2[tid];
    #pragma unroll
    for (int gi = 0; gi < 8; ++gi) {
        float s = 0.f;
        for (int n = 0; n < PP; ++n) {
            float v = fmaf(scv, h2[((size_t)(g0+gi)*PP + n)*F2 + tid], shv);
            s += lrelu(v);
        }
        pooled[gi][tid] = s * (1.f/18.f);
    }
    __syncthreads();
    #pragma unroll
    for (int jo = 0; jo < 2; ++jo) {
        int j = tid + jo*256;
        float acc[8];
        float bv = bfc1[j];
        #pragma unroll
        for (int gi = 0; gi < 8; ++gi) acc[gi] = bv;
        for (int k = 0; k < F2; ++k) {
            float w = Wfc1[k*512 + j];
            #pragma unroll
            for (int gi = 0; gi < 8; ++gi) acc[gi] = fmaf(pooled[gi][k], w, acc[gi]);
        }
        #pragma unroll
        for (int gi = 0; gi < 8; ++gi) y1[gi][j] = lrelu(acc[gi]);
    }
    __syncthreads();
    {
        int j = tid & 127, kh = tid >> 7;
        float acc[8] = {0,0,0,0,0,0,0,0};
        for (int k = kh*256; k < kh*256 + 256; ++k) {
            float w = Wfc2[k*128 + j];
            #pragma unroll
            for (int gi = 0; gi < 8; ++gi) acc[gi] = fmaf(y1[gi][k], w, acc[gi]);
        }
        if (kh == 1) {
            #pragma unroll
            for (int gi = 0; gi < 8; ++gi) pooled[gi][j] = acc[gi];
        }
        __syncthreads();
        if (kh == 0) {
            float w3 = Wfc3[j], bv = bfc2[j];
            #pragma unroll
            for (int gi = 0; gi < 8; ++gi)
                y2[gi][j] = lrelu(acc[gi] + pooled[gi][j] + bv) * w3;
        }
    }
    __syncthreads();
    {
        int gi = tid >> 5, lx = tid & 31;
        float p = y2[gi][lx] + y2[gi][lx+32] + y2[gi][lx+64] + y2[gi][lx+96];
        p += __shfl_xor(p, 1); p += __shfl_xor(p, 2); p += __shfl_xor(p, 4);
        p += __shfl_xor(p, 8); p += __shfl_xor(p, 16);
        if (lx == 0) out[g0 + gi] = p + bfc3[0];
    }
}

extern "C" void kernel_launch(void* const* d_in, const int* in_sizes, int n_in,
                              void* d_out, int out_size, void* d_ws, size_t ws_size,
                              hipStream_t stream)
{
    const float* x     = (const float*)d_in[0];
    const float* eattr = (const float*)d_in[1];
    const float* W1l   = (const float*)d_in[4];
    const float* b1l   = (const float*)d_in[5];
    const float* W1r   = (const float*)d_in[6];
    const float* b1r   = (const float*)d_in[7];
    const float* We1   = (const float*)d_in[8];
    const float* att1  = (const float*)d_in[9];
    const float* bias1 = (const float*)d_in[10];
    const float* W2l   = (const float*)d_in[11];
    const float* b2l   = (const float*)d_in[12];
    const float* W2r   = (const float*)d_in[13];
    const float* b2r   = (const float*)d_in[14];
    const float* We2   = (const float*)d_in[15];
    const float* att2  = (const float*)d_in[16];
    const float* bias2 = (const float*)d_in[17];
    const float* g1    = (const float*)d_in[18];
    const float* be1   = (const float*)d_in[19];
    const float* g2    = (const float*)d_in[20];
    const float* be2   = (const float*)d_in[21];
    const float* Wfc1  = (const float*)d_in[22];
    const float* bfc1  = (const float*)d_in[23];
    const float* Wfc2  = (const float*)d_in[24];
    const float* bfc2  = (const float*)d_in[25];
    const float* Wfc3  = (const float*)d_in[26];
    const float* bfc3  = (const float*)d_in[27];
    float* out = (float*)d_out;

    float* ws = (float*)d_ws;
    float* h1 = ws;                                  // NNODE*128 f32
    float* h2 = h1 + (size_t)NNODE*F1;               // NNODE*256 f32
    float* st = h2 + (size_t)NNODE*F2;               // 1536 f32 stats
    float* biascat = st + 1536;                      // 512 f32
    u16* xlr = (u16*)(biascat + 512);                // NNODE*512 bf16
    u16* wbt = xlr + (size_t)NNODE*F2*2;             // 512*128 bf16

    float* sum1 = st,     *ss1 = st+128, *sc1 = st+256,  *sh1 = st+384;
    float* sum2 = st+512, *ss2 = st+768, *sc2 = st+1024, *sh2 = st+1280;

    prep_w<<<259, 256, 0, stream>>>(W2l, W2r, b2l, b2r, wbt, biascat, st);
    gat1_kernel<<<GG, 256, 0, stream>>>(x, eattr, W1l, b1l, W1r, b1r, We1, att1, bias1, h1, sum1, ss1);
    bnfin<<<1, 128, 0, stream>>>(sum1, ss1, g1, be1, sc1, sh1, F1, 1.f/NNODE);
    gemm2_kernel<<<(NNODE/64)*8, 256, 0, stream>>>(h1, sc1, sh1, wbt, biascat, xlr);
    gat2_attn<<<GG, 256, 0, stream>>>(xlr, eattr, We2, att2, bias2, h2, sum2, ss2);
    bnfin<<<1, 256, 0, stream>>>(sum2, ss2, g2, be2, sc2, sh2, F2, 1.f/NNODE);
    mlp_kernel<<<GG/8, 256, 0, stream>>>(h2, sc2, sh2, Wfc1, bfc1, Wfc2, bfc2, Wfc3, bfc3, out);
}

// Round 7
// 365.833 us; speedup vs baseline: 1.5098x; 1.5098x over previous
//
#include <hip/hip_runtime.h>
#include <hip/hip_fp16.h>
#include <cstddef>

#define GG 2048
#define PP 18
#define NNODE (GG*PP)      // 36864
#define EPG 306            // directed edges per graph (17*18)
#define F1 128             // H1*C1
#define F2 256             // H2*C2
#define INF 6

typedef unsigned short u16;
typedef unsigned int u32;
typedef __attribute__((ext_vector_type(8))) short short8;   // 8 bf16
typedef __attribute__((ext_vector_type(4))) float f32x4;

__device__ __forceinline__ float lrelu(float v) { return v > 0.f ? v : 0.01f * v; }

__device__ __forceinline__ u16 f2b(float x) {            // fp32 -> bf16 RNE
    union { float f; unsigned u; } c; c.f = x;
    unsigned r = c.u + 0x7FFF + ((c.u >> 16) & 1);
    return (u16)(r >> 16);
}
__device__ __forceinline__ u32 pack_h2(float a, float b) {   // 2xf32 -> packed fp16
    __half2 h = __floats2half2_rn(a, b);
    return *(u32*)&h;
}
__device__ __forceinline__ float2 unpack_h2(u32 u) {
    __half2 h = *(__half2*)&u;
    return __half22float2(h);
}
// packed bf16 pair -> 2 floats (lo = even channel)
__device__ __forceinline__ float bpk_lo(u32 u) { return __uint_as_float(u << 16); }
__device__ __forceinline__ float bpk_hi(u32 u) { return __uint_as_float(u & 0xffff0000u); }

// ================= layer 1: GATv2 (6 -> 4x32) + BN1 stats, one block/graph =================
// R4 structure; xl/xr stored as packed fp16 pairs (halves LDS bytes+instrs).
__global__ __launch_bounds__(256) void gat1_kernel(
    const float* __restrict__ x, const float* __restrict__ eattr,
    const float* __restrict__ W1l, const float* __restrict__ b1l,
    const float* __restrict__ W1r, const float* __restrict__ b1r,
    const float* __restrict__ We1, const float* __restrict__ att1,
    const float* __restrict__ bias1, float* __restrict__ h1,
    float* __restrict__ sum1, float* __restrict__ ss1)
{
    __shared__ float xs[PP*INF];
    __shared__ float wl[INF*F1], wr[INF*F1];
    __shared__ float bl[F1], br[F1], we[F1], att[F1];
    __shared__ float ea[PP*PP];            // ea[s*18+d]
    __shared__ u32 xlp[PP*64], xrp[PP*64]; // fp16 pairs, row stride 64
    __shared__ float alpha[PP*PP*4];       // [d*72 + s*4 + h]
    __shared__ float2 sst[256], qst[256];
    const int g = blockIdx.x, tid = threadIdx.x;

    if (tid < PP*INF) xs[tid] = x[g*PP*INF + tid];
    for (int i = tid; i < INF*F1; i += 256) { wl[i] = W1l[i]; wr[i] = W1r[i]; }
    if (tid < F1) { bl[tid]=b1l[tid]; br[tid]=b1r[tid]; we[tid]=We1[tid]; att[tid]=att1[tid]; }
    for (int t = tid; t < EPG; t += 256) {
        int s = t/17, pos = t%17;
        int d = pos + (pos >= s);
        ea[s*PP + d] = eattr[g*EPG + t];
    }
    __syncthreads();
    if (tid < PP) {   // self-loop attr = mean of incoming
        float sum = 0.f;
        for (int s = 0; s < PP; ++s) if (s != tid) sum += ea[s*PP + tid];
        ea[tid*PP + tid] = sum * (1.f/17.f);
    }
    __syncthreads();
    // projections: thread owns a column pair
    for (int slot = tid; slot < PP*64; slot += 256) {
        int n = slot >> 6, jp = slot & 63, j = jp*2;
        float al0 = bl[j], al1 = bl[j+1], ar0 = br[j], ar1 = br[j+1];
        #pragma unroll
        for (int k = 0; k < INF; ++k) {
            float xv = xs[n*INF + k];
            al0 = fmaf(xv, wl[k*F1 + j],   al0);
            al1 = fmaf(xv, wl[k*F1 + j+1], al1);
            ar0 = fmaf(xv, wr[k*F1 + j],   ar0);
            ar1 = fmaf(xv, wr[k*F1 + j+1], ar1);
        }
        xlp[n*64 + jp] = pack_h2(al0, al1);
        xrp[n*64 + jp] = pack_h2(ar0, ar1);
    }
    __syncthreads();
    // alpha: thread <-> one (d,s,h); rotated packed-pair reads (16 pairs/head)
    for (int t = tid; t < PP*PP*4; t += 256) {
        int h = t & 3, s = (t >> 2) % PP, d = t / (PP*4);
        float eav = ea[s*PP + d];
        const u32* xls = &xlp[s*64 + h*16];
        const u32* xrd = &xrp[d*64 + h*16];
        const float* wec = &we[h*32];
        const float* atc = &att[h*32];
        float acc = 0.f;
        #pragma unroll 8
        for (int cc = 0; cc < 16; ++cc) {
            int p = (cc + t) & 15;
            float2 xl2 = unpack_h2(xls[p]);
            float2 xr2 = unpack_h2(xrd[p]);
            float2 w2 = *(const float2*)&wec[2*p];
            float2 a2 = *(const float2*)&atc[2*p];
            acc = fmaf(lrelu(fmaf(eav, w2.x, xl2.x + xr2.x)), a2.x, acc);
            acc = fmaf(lrelu(fmaf(eav, w2.y, xl2.y + xr2.y)), a2.y, acc);
        }
        alpha[t] = acc;
    }
    __syncthreads();
    if (tid < PP*4) {                      // softmax over s per (d,h)
        int d = tid >> 2, h = tid & 3;
        int base = d*(PP*4) + h;
        float m = -1e30f;
        for (int s = 0; s < PP; ++s) m = fmaxf(m, alpha[base + s*4]);
        float sum = 0.f;
        for (int s = 0; s < PP; ++s) sum += __expf(alpha[base + s*4] - m);
        float inv = 1.f/(sum + 1e-16f);
        for (int s = 0; s < PP; ++s)
            alpha[base + s*4] = __expf(alpha[base + s*4] - m) * inv;
    }
    __syncthreads();
    // PV: thread owns fixed column pair jp = tid&63
    float2 s_loc = {0,0}, q_loc = {0,0};
    {
        const int jp = tid & 63, h = jp >> 4, c0 = jp*2;
        const float2 b2v = *(const float2*)&bias1[c0];
        for (int slot = tid; slot < PP*64; slot += 256) {
            int d = slot >> 6;
            float2 acc = b2v;
            for (int s = 0; s < PP; ++s) {
                float av = alpha[d*(PP*4) + s*4 + h];   // broadcast among 16 lanes
                u32 u = xlp[s*64 + jp];
                float2 xl2 = unpack_h2(u);
                acc.x = fmaf(av, xl2.x, acc.x);
                acc.y = fmaf(av, xl2.y, acc.y);
            }
            *(float2*)&h1[(size_t)g*(PP*F1) + d*F1 + c0] = acc;
            s_loc.x += acc.x; s_loc.y += acc.y;
            q_loc.x = fmaf(acc.x, acc.x, q_loc.x);
            q_loc.y = fmaf(acc.y, acc.y, q_loc.y);
        }
    }
    __syncthreads();
    sst[tid] = s_loc; qst[tid] = q_loc;
    __syncthreads();
    if (tid < 64) {                        // lane owns columns 2*tid, 2*tid+1
        float2 S = {0,0}, Q = {0,0};
        #pragma unroll
        for (int m = 0; m < 4; ++m) {
            float2 a = sst[tid + 64*m], b = qst[tid + 64*m];
            S.x += a.x; S.y += a.y; Q.x += b.x; Q.y += b.y;
        }
        atomicAdd(&sum1[2*tid],   S.x); atomicAdd(&sum1[2*tid+1], S.y);
        atomicAdd(&ss1[2*tid],    Q.x); atomicAdd(&ss1[2*tid+1],  Q.y);
    }
}

// ================= BN finalize =================
__global__ void bnfin(const float* __restrict__ sum, const float* __restrict__ ss,
                      const float* __restrict__ gamma, const float* __restrict__ beta,
                      float* __restrict__ sc, float* __restrict__ sh, int C, float invN)
{
    int c = threadIdx.x + blockIdx.x*blockDim.x;
    if (c < C) {
        float mu = sum[c]*invN;
        float var = ss[c]*invN - mu*mu;
        float s = gamma[c]*rsqrtf(var + 1e-5f);
        sc[c] = s;
        sh[c] = beta[c] - mu*s;
    }
}

// ================= prep: W2 -> bf16 transposed, bias concat, zero stats =================
__global__ void prep_w(const float* __restrict__ W2l, const float* __restrict__ W2r,
                       const float* __restrict__ b2l, const float* __restrict__ b2r,
                       u16* __restrict__ wbt, float* __restrict__ biascat,
                       float* __restrict__ st)
{
    int t = blockIdx.x*blockDim.x + threadIdx.x;
    if (t < 1536) st[t] = 0.f;
    if (t < 512*128) {
        int c = t >> 7, k = t & 127;
        float v = (c < 256) ? W2l[k*256 + c] : W2r[k*256 + (c-256)];
        wbt[t] = f2b(v);           // wbt[c][k]
    } else if (t < 512*128 + 512) {
        int c = t - 512*128;
        biascat[c] = (c < 256) ? b2l[c] : b2r[c-256];
    }
}

// ================= layer-2 projection GEMM (bn1+lrelu fused into A-stage) =================
__global__ __launch_bounds__(256) void gemm2_kernel(
    const float* __restrict__ h1, const float* __restrict__ sc1, const float* __restrict__ sh1,
    const u16* __restrict__ wbt, const float* __restrict__ biascat, u16* __restrict__ xlr)
{
    __shared__ u16 As[64*128];
    __shared__ u16 Bs[64*128];
    __shared__ float scs[F1], shs[F1];
    const int b = blockIdx.x;
    const int bm = b >> 3, bn = b & 7;
    const int r0 = bm*64, c0 = bn*64;
    const int tid = threadIdx.x;

    if (tid < F1) { scs[tid] = sc1[tid]; shs[tid] = sh1[tid]; }
    __syncthreads();
    for (int i = tid*8; i < 64*128; i += 256*8) {
        int r = i >> 7, c = i & 127;
        float4 v0 = *(const float4*)&h1[(size_t)(r0+r)*128 + c];
        float4 v1 = *(const float4*)&h1[(size_t)(r0+r)*128 + c + 4];
        short8 a;
        a[0] = (short)f2b(lrelu(fmaf(scs[c+0], v0.x, shs[c+0])));
        a[1] = (short)f2b(lrelu(fmaf(scs[c+1], v0.y, shs[c+1])));
        a[2] = (short)f2b(lrelu(fmaf(scs[c+2], v0.z, shs[c+2])));
        a[3] = (short)f2b(lrelu(fmaf(scs[c+3], v0.w, shs[c+3])));
        a[4] = (short)f2b(lrelu(fmaf(scs[c+4], v1.x, shs[c+4])));
        a[5] = (short)f2b(lrelu(fmaf(scs[c+5], v1.y, shs[c+5])));
        a[6] = (short)f2b(lrelu(fmaf(scs[c+6], v1.z, shs[c+6])));
        a[7] = (short)f2b(lrelu(fmaf(scs[c+7], v1.w, shs[c+7])));
        int idx = i ^ ((r & 7) << 3);
        *reinterpret_cast<short8*>(&As[idx]) = a;
        *reinterpret_cast<short8*>(&Bs[idx]) =
            *reinterpret_cast<const short8*>(&wbt[(size_t)(c0+r)*128 + c]);
    }
    __syncthreads();

    const int w = tid >> 6, l = tid & 63;
    const int lr = l & 15, lk = (l >> 4) * 8;
    const int ar = w*16 + lr;
    f32x4 acc[4] = {f32x4{0,0,0,0}, f32x4{0,0,0,0}, f32x4{0,0,0,0}, f32x4{0,0,0,0}};

    #pragma unroll
    for (int kk = 0; kk < 4; ++kk) {
        int k0 = kk*32 + lk;
        short8 a = *reinterpret_cast<const short8*>(&As[(ar*128 + k0) ^ ((ar & 7) << 3)]);
        #pragma unroll
        for (int n = 0; n < 4; ++n) {
            int br = n*16 + lr;
            short8 bf = *reinterpret_cast<const short8*>(&Bs[(br*128 + k0) ^ ((br & 7) << 3)]);
            acc[n] = __builtin_amdgcn_mfma_f32_16x16x32_bf16(a, bf, acc[n], 0, 0, 0);
        }
    }
    const int rbase = r0 + w*16 + (l >> 4)*4;
    #pragma unroll
    for (int n = 0; n < 4; ++n) {
        int C = c0 + n*16 + lr;
        float bv = biascat[C];
        #pragma unroll
        for (int j = 0; j < 4; ++j) {
            xlr[(size_t)(rbase + j)*512 + C] = f2b(acc[n][j] + bv);
        }
    }
}

// ================= layer 2 attention + BN2 stats, one block/graph =================
// R4 structure; xl/xr kept as raw bf16 pairs (lossless — data is already bf16).
__global__ __launch_bounds__(256) void gat2_attn(
    const u16* __restrict__ xlr, const float* __restrict__ eattr,
    const float* __restrict__ We2, const float* __restrict__ att2,
    const float* __restrict__ bias2, float* __restrict__ h2,
    float* __restrict__ sum2, float* __restrict__ ss2)
{
    __shared__ u32 xlp[PP*128], xrp[PP*128];   // bf16 pairs, row stride 128
    __shared__ float ea[PP*PP];
    __shared__ float alpha[PP*PP*4];           // [d*72 + s*4 + h]
    __shared__ float we[F2], att[F2];
    __shared__ float2 sst[256], qst[256];
    const int g = blockIdx.x, tid = threadIdx.x;

    if (tid < F2) { we[tid] = We2[tid]; att[tid] = att2[tid]; }
    for (int i4 = tid; i4 < PP*128; i4 += 256) {   // 2 pairs (8B) per iter
        int n = i4 >> 7, q = (i4 & 127)*2;         // q = first pair idx in [0,256)
        uint2 v = *(const uint2*)&xlr[(size_t)(g*PP + n)*512 + q*2];
        if (q < 128) { xlp[n*128 + q] = v.x; xlp[n*128 + q+1] = v.y; }
        else         { xrp[n*128 + q-128] = v.x; xrp[n*128 + q-127] = v.y; }
    }
    for (int t = tid; t < EPG; t += 256) {
        int s = t/17, pos = t%17;
        int d = pos + (pos >= s);
        ea[s*PP + d] = eattr[g*EPG + t];
    }
    __syncthreads();
    if (tid < PP) {
        float sum = 0.f;
        for (int s = 0; s < PP; ++s) if (s != tid) sum += ea[s*PP + tid];
        ea[tid*PP + tid] = sum * (1.f/17.f);
    }
    __syncthreads();
    // alpha: thread <-> one (d,s,h); rotated packed-pair reads (32 pairs/head)
    for (int t = tid; t < PP*PP*4; t += 256) {
        int h = t & 3, s = (t >> 2) % PP, d = t / (PP*4);
        float eav = ea[s*PP + d];
        const u32* xls = &xlp[s*128 + h*32];
        const u32* xrd = &xrp[d*128 + h*32];
        const float* wec = &we[h*64];
        const float* atc = &att[h*64];
        float acc = 0.f;
        #pragma unroll 8
        for (int cc = 0; cc < 32; ++cc) {
            int p = (cc + t) & 31;
            u32 ul = xls[p], ur = xrd[p];
            float2 w2 = *(const float2*)&wec[2*p];
            float2 a2 = *(const float2*)&atc[2*p];
            acc = fmaf(lrelu(fmaf(eav, w2.x, bpk_lo(ul) + bpk_lo(ur))), a2.x, acc);
            acc = fmaf(lrelu(fmaf(eav, w2.y, bpk_hi(ul) + bpk_hi(ur))), a2.y, acc);
        }
        alpha[t] = acc;
    }
    __syncthreads();
    if (tid < PP*4) {
        int d = tid >> 2, h = tid & 3;
        int base = d*(PP*4) + h;
        float m = -1e30f;
        for (int s = 0; s < PP; ++s) m = fmaxf(m, alpha[base + s*4]);
        float sum = 0.f;
        for (int s = 0; s < PP; ++s) sum += __expf(alpha[base + s*4] - m);
        float inv = 1.f/(sum + 1e-16f);
        for (int s = 0; s < PP; ++s)
            alpha[base + s*4] = __expf(alpha[base + s*4] - m) * inv;
    }
    __syncthreads();
    // PV: thread owns fixed column pair jp = tid&127
    float2 s_loc = {0,0}, q_loc = {0,0};
    {
        const int jp = tid & 127, h = jp >> 5, c0 = jp*2;
        const float2 b2v = *(const float2*)&bias2[c0];
        for (int slot = tid; slot < PP*128; slot += 256) {
            int d = slot >> 7;
            float2 acc = b2v;
            for (int s = 0; s < PP; ++s) {
                float av = alpha[d*(PP*4) + s*4 + h];   // broadcast among 32 lanes
                u32 u = xlp[s*128 + jp];
                acc.x = fmaf(av, bpk_lo(u), acc.x);
                acc.y = fmaf(av, bpk_hi(u), acc.y);
            }
            *(float2*)&h2[(size_t)g*(PP*F2) + d*F2 + c0] = acc;
            s_loc.x += acc.x; s_loc.y += acc.y;
            q_loc.x = fmaf(acc.x, acc.x, q_loc.x);
            q_loc.y = fmaf(acc.y, acc.y, q_loc.y);
        }
    }
    __syncthreads();
    sst[tid] = s_loc; qst[tid] = q_loc;
    __syncthreads();
    if (tid < 128) {                       // lane owns columns 2*tid, 2*tid+1
        float2 a = sst[tid], b = sst[tid+128];
        float2 c = qst[tid], d = qst[tid+128];
        atomicAdd(&sum2[2*tid],   a.x + b.x); atomicAdd(&sum2[2*tid+1], a.y + b.y);
        atomicAdd(&ss2[2*tid],    c.x + d.x); atomicAdd(&ss2[2*tid+1],  c.y + d.y);
    }
}

// ================= BN2+lrelu + mean-pool + MLP head, 8 graphs/block =================
__global__ __launch_bounds__(256) void mlp_kernel(
    const float* __restrict__ h2, const float* __restrict__ sc2, const float* __restrict__ sh2,
    const float* __restrict__ Wfc1, const float* __restrict__ bfc1,
    const float* __restrict__ Wfc2, const float* __restrict__ bfc2,
    const float* __restrict__ Wfc3, const float* __restrict__ bfc3,
    float* __restrict__ out)
{
    __shared__ float pooled[8][F2];
    __shared__ float y1[8][512];
    __shared__ float y2[8][128];
    const int g0 = blockIdx.x * 8, tid = threadIdx.x;
    const float scv = sc2[tid], shv = sh2[tid];
    #pragma unroll
    for (int gi = 0; gi < 8; ++gi) {
        float s = 0.f;
        for (int n = 0; n < PP; ++n) {
            float v = fmaf(scv, h2[((size_t)(g0+gi)*PP + n)*F2 + tid], shv);
            s += lrelu(v);
        }
        pooled[gi][tid] = s * (1.f/18.f);
    }
    __syncthreads();
    #pragma unroll
    for (int jo = 0; jo < 2; ++jo) {
        int j = tid + jo*256;
        float acc[8];
        float bv = bfc1[j];
        #pragma unroll
        for (int gi = 0; gi < 8; ++gi) acc[gi] = bv;
        for (int k = 0; k < F2; ++k) {
            float w = Wfc1[k*512 + j];
            #pragma unroll
            for (int gi = 0; gi < 8; ++gi) acc[gi] = fmaf(pooled[gi][k], w, acc[gi]);
        }
        #pragma unroll
        for (int gi = 0; gi < 8; ++gi) y1[gi][j] = lrelu(acc[gi]);
    }
    __syncthreads();
    {
        int j = tid & 127, kh = tid >> 7;
        float acc[8] = {0,0,0,0,0,0,0,0};
        for (int k = kh*256; k < kh*256 + 256; ++k) {
            float w = Wfc2[k*128 + j];
            #pragma unroll
            for (int gi = 0; gi < 8; ++gi) acc[gi] = fmaf(y1[gi][k], w, acc[gi]);
        }
        if (kh == 1) {
            #pragma unroll
            for (int gi = 0; gi < 8; ++gi) pooled[gi][j] = acc[gi];
        }
        __syncthreads();
        if (kh == 0) {
            float w3 = Wfc3[j], bv = bfc2[j];
            #pragma unroll
            for (int gi = 0; gi < 8; ++gi)
                y2[gi][j] = lrelu(acc[gi] + pooled[gi][j] + bv) * w3;
        }
    }
    __syncthreads();
    {
        int gi = tid >> 5, lx = tid & 31;
        float p = y2[gi][lx] + y2[gi][lx+32] + y2[gi][lx+64] + y2[gi][lx+96];
        p += __shfl_xor(p, 1); p += __shfl_xor(p, 2); p += __shfl_xor(p, 4);
        p += __shfl_xor(p, 8); p += __shfl_xor(p, 16);
        if (lx == 0) out[g0 + gi] = p + bfc3[0];
    }
}

extern "C" void kernel_launch(void* const* d_in, const int* in_sizes, int n_in,
                              void* d_out, int out_size, void* d_ws, size_t ws_size,
                              hipStream_t stream)
{
    const float* x     = (const float*)d_in[0];
    const float* eattr = (const float*)d_in[1];
    const float* W1l   = (const float*)d_in[4];
    const float* b1l   = (const float*)d_in[5];
    const float* W1r   = (const float*)d_in[6];
    const float* b1r   = (const float*)d_in[7];
    const float* We1   = (const float*)d_in[8];
    const float* att1  = (const float*)d_in[9];
    const float* bias1 = (const float*)d_in[10];
    const float* W2l   = (const float*)d_in[11];
    const float* b2l   = (const float*)d_in[12];
    const float* W2r   = (const float*)d_in[13];
    const float* b2r   = (const float*)d_in[14];
    const float* We2   = (const float*)d_in[15];
    const float* att2  = (const float*)d_in[16];
    const float* bias2 = (const float*)d_in[17];
    const float* g1    = (const float*)d_in[18];
    const float* be1   = (const float*)d_in[19];
    const float* g2    = (const float*)d_in[20];
    const float* be2   = (const float*)d_in[21];
    const float* Wfc1  = (const float*)d_in[22];
    const float* bfc1  = (const float*)d_in[23];
    const float* Wfc2  = (const float*)d_in[24];
    const float* bfc2  = (const float*)d_in[25];
    const float* Wfc3  = (const float*)d_in[26];
    const float* bfc3  = (const float*)d_in[27];
    float* out = (float*)d_out;

    float* ws = (float*)d_ws;
    float* h1 = ws;                                  // NNODE*128 f32
    float* h2 = h1 + (size_t)NNODE*F1;               // NNODE*256 f32
    float* st = h2 + (size_t)NNODE*F2;               // 1536 f32 stats
    float* biascat = st + 1536;                      // 512 f32
    u16* xlr = (u16*)(biascat + 512);                // NNODE*512 bf16
    u16* wbt = xlr + (size_t)NNODE*F2*2;             // 512*128 bf16

    float* sum1 = st,     *ss1 = st+128, *sc1 = st+256,  *sh1 = st+384;
    float* sum2 = st+512, *ss2 = st+768, *sc2 = st+1024, *sh2 = st+1280;

    prep_w<<<259, 256, 0, stream>>>(W2l, W2r, b2l, b2r, wbt, biascat, st);
    gat1_kernel<<<GG, 256, 0, stream>>>(x, eattr, W1l, b1l, W1r, b1r, We1, att1, bias1, h1, sum1, ss1);
    bnfin<<<1, 128, 0, stream>>>(sum1, ss1, g1, be1, sc1, sh1, F1, 1.f/NNODE);
    gemm2_kernel<<<(NNODE/64)*8, 256, 0, stream>>>(h1, sc1, sh1, wbt, biascat, xlr);
    gat2_attn<<<GG, 256, 0, stream>>>(xlr, eattr, We2, att2, bias2, h2, sum2, ss2);
    bnfin<<<1, 256, 0, stream>>>(sum2, ss2, g2, be2, sc2, sh2, F2, 1.f/NNODE);
    mlp_kernel<<<GG/8, 256, 0, stream>>>(h2, sc2, sh2, Wfc1, bfc1, Wfc2, bfc2, Wfc3, bfc3, out);
}